// Round 7
// baseline (855.633 us; speedup 1.0000x reference)
//
#include <hip/hip_runtime.h>
#include <hip/hip_bf16.h>

using bf16 = __hip_bfloat16;
typedef __bf16 bfv8 __attribute__((ext_vector_type(8)));
typedef float f32x4 __attribute__((ext_vector_type(4)));

constexpr int B = 4, S = 4096, D = 1024, H = 16, DH = 64, WIN = 512, NW = S / WIN;
constexpr int M_ROWS = B * S;   // 16384
constexpr int FCH = 8192;       // FFN row chunk (hb = FCH*4096*2 = 64 MiB in d_out)
constexpr int NFCH = M_ROWS / FCH;
constexpr int QCH = 8192;       // QKV row chunk (srcb = QCH*1024*2 = 16 MiB)
constexpr int NQCH = M_ROWS / QCH;

#define DEV static __device__ __forceinline__

DEV float bf2f(bf16 x) { return __bfloat162float(x); }

DEV unsigned pack2bf(float a, float b) {
    union { __hip_bfloat162 h2; unsigned u; } cv;
    cv.h2.x = __float2bfloat16(a);
    cv.h2.y = __float2bfloat16(b);
    return cv.u;
}

DEV void store_val(float* p, float v) { *p = v; }
DEV void store_val(bf16* p, float v) { *p = __float2bfloat16(v); }

// async global->LDS, 16B per lane; LDS dest = wave-uniform base + lane*16
DEV void gload16(const bf16* g, bf16* l) {
    __builtin_amdgcn_global_load_lds(
        (const __attribute__((address_space(1))) unsigned int*)g,
        (__attribute__((address_space(3))) unsigned int*)l, 16, 0, 0);
}

// ---------------------------------------------------------------------------
// f32 -> bf16 bulk convert (8 elems/thread)
// ---------------------------------------------------------------------------
__global__ __launch_bounds__(256) void f2b_kernel(
    const float* __restrict__ in, bf16* __restrict__ out, int n8) {
    const int i = blockIdx.x * 256 + threadIdx.x;
    if (i >= n8) return;
    const float* p = in + (long)i * 8;
    const float4 a = *(const float4*)p;
    const float4 b = *(const float4*)(p + 4);
    uint4 pk;
    pk.x = pack2bf(a.x, a.y); pk.y = pack2bf(a.z, a.w);
    pk.z = pack2bf(b.x, b.y); pk.w = pack2bf(b.z, b.w);
    *(uint4*)(out + (long)i * 8) = pk;
}

// ---------------------------------------------------------------------------
// 256-wide pipelined MFMA GEMM (T2+T3/T4+T5+T1).
// 8 waves (2 row-groups x 4 col-groups), 512 thr, BM=256, BN=NREP*64, BK=64.
// Double-buffered LDS (128/96 KiB), counted vmcnt: prologue stages tiles 0,1;
// iter t waits vmcnt(LPS) = tile t landed while tile t+1's LPS loads stay in
// flight (never drained to 0 in-loop); after the 4 quadrant phases the just-
// freed buffer is restaged with tile t+2. Raw s_barrier + sched_barrier(0)
// fencing (no __syncthreads -> no compiler vmcnt(0) drain). T2 swizzle is the
// round-6-verified mapping: linear LDS dest, pre-swizzled global source col
// ((tid&7)^(row&7))*8, ds_read slot ((kk*4+quad)^(l16&7))*8.
// Safety: all loop bounds uniform; frag ds_reads retire before each phase's
// MFMA (compiler lgkmcnt) which retires before the phase barrier, so the
// post-loop STAGE into buf[cur] cannot race readers.
// ---------------------------------------------------------------------------
template <typename TO, bool RELU, bool RESID, bool QKV, int NREP>
__global__ __launch_bounds__(512, 1) void gemm256(
    const bf16* __restrict__ A, const bf16* __restrict__ Wt,
    const float* __restrict__ bias, const bf16* __restrict__ resid,
    TO* __restrict__ out, int K, int N,
    TO* __restrict__ outk, TO* __restrict__ outv,
    const float* __restrict__ biask, const float* __restrict__ biasv) {
    constexpr int BM = 256;
    constexpr int BN = NREP * 64;        // 256 (NREP=4) or 128 (NREP=2)
    constexpr int ASZ = BM * 64;
    constexpr int BSZ = BN * 64;
    constexpr int LPS = 4 + BN / 64;     // gloads per STAGE (8 or 6)
    __shared__ bf16 Al[2][ASZ];
    __shared__ bf16 Bl[2][BSZ];

    const int tid = threadIdx.x;
    const int wid = tid >> 6, lane = tid & 63;
    const int quad = lane >> 4, l16 = lane & 15;
    const int wr = wid >> 2, wc = wid & 3;

    // T1 XCD-chunked swizzle (grids all %8==0 -> bijective)
    const int nwg = gridDim.x * gridDim.y;
    const int orig = blockIdx.y * gridDim.x + blockIdx.x;
    const int swz = (orig & 7) * (nwg >> 3) + (orig >> 3);
    const int bx = swz % gridDim.x;
    const int by = swz / gridDim.x;
    const long m0 = (long)by * BM;
    const long n0 = (long)bx * BN;

    // staging map: pass j covers rows j*64 + (tid>>3); global col pre-swizzled
    const int srow = tid >> 3;
    const int scol = ((tid & 7) ^ (srow & 7)) * 8;

    const int nt = K >> 6;

    f32x4 acc[8][NREP] = {};

    auto STAGE = [&](int tt, int buf) {
        const long k0 = (long)tt * 64;
#pragma unroll
        for (int j = 0; j < 4; ++j)
            gload16(A + (m0 + j * 64 + srow) * (long)K + k0 + scol,
                    (bf16*)((char*)&Al[buf][0] + j * 8192 + wid * 1024));
#pragma unroll
        for (int j = 0; j < BN / 64; ++j)
            gload16(Wt + (n0 + j * 64 + srow) * (long)K + k0 + scol,
                    (bf16*)((char*)&Bl[buf][0] + j * 8192 + wid * 1024));
    };

    // prologue: tiles 0 and 1 in flight (2*LPS loads)
    STAGE(0, 0);
    STAGE(1, 1);

    for (int t = 0; t < nt; ++t) {
        const int cur = t & 1;
        // counted wait: tile t's LPS loads retired; tile t+1's may stay in flight
        if (t < nt - 1) {
            if constexpr (LPS == 8) asm volatile("s_waitcnt vmcnt(8)" ::: "memory");
            else                    asm volatile("s_waitcnt vmcnt(6)" ::: "memory");
        } else {
            asm volatile("s_waitcnt vmcnt(0)" ::: "memory");
        }
        __builtin_amdgcn_sched_barrier(0);
        __builtin_amdgcn_s_barrier();
        __builtin_amdgcn_sched_barrier(0);

        const bf16* Ab = &Al[cur][0];
        const bf16* Bb = &Bl[cur][0];
#pragma unroll
        for (int mh = 0; mh < 2; ++mh) {
            bfv8 af[4][2];
#pragma unroll
            for (int mi = 0; mi < 4; ++mi)
#pragma unroll
                for (int kk = 0; kk < 2; ++kk)
                    af[mi][kk] = *(const bfv8*)&Ab[
                        (wr * 128 + mh * 64 + mi * 16 + l16) * 64 +
                        ((kk * 4 + quad) ^ (l16 & 7)) * 8];
#pragma unroll
            for (int nh = 0; nh < 2; ++nh) {
                bfv8 bfr[NREP / 2][2];
#pragma unroll
                for (int ni = 0; ni < NREP / 2; ++ni)
#pragma unroll
                    for (int kk = 0; kk < 2; ++kk)
                        bfr[ni][kk] = *(const bfv8*)&Bb[
                            (wc * (NREP * 16) + (nh * (NREP / 2) + ni) * 16 + l16) * 64 +
                            ((kk * 4 + quad) ^ (l16 & 7)) * 8];
                __builtin_amdgcn_s_setprio(1);
#pragma unroll
                for (int mi = 0; mi < 4; ++mi)
#pragma unroll
                    for (int ni = 0; ni < NREP / 2; ++ni)
#pragma unroll
                        for (int kk = 0; kk < 2; ++kk)
                            acc[mh * 4 + mi][nh * (NREP / 2) + ni] =
                                __builtin_amdgcn_mfma_f32_16x16x32_bf16(
                                    af[mi][kk], bfr[ni][kk],
                                    acc[mh * 4 + mi][nh * (NREP / 2) + ni], 0, 0, 0);
                __builtin_amdgcn_s_setprio(0);
                __builtin_amdgcn_sched_barrier(0);
                __builtin_amdgcn_s_barrier();
                __builtin_amdgcn_sched_barrier(0);
            }
        }
        // restage just-freed buffer with tile t+2 (flies across iter t+1)
        if (t + 2 < nt) STAGE(t + 2, cur);
    }

    // epilogue
#pragma unroll
    for (int mf = 0; mf < 8; ++mf) {
#pragma unroll
        for (int r = 0; r < 4; ++r) {
            const long m = m0 + wr * 128 + mf * 16 + quad * 4 + r;
#pragma unroll
            for (int nf = 0; nf < NREP; ++nf) {
                const long n = n0 + wc * (NREP * 16) + nf * 16 + l16;
                float val = acc[mf][nf][r];
                if constexpr (QKV) {
                    const int sel = (int)(n >> 10);
                    const long nn = n & 1023;
                    TO* op = sel == 0 ? out : (sel == 1 ? outk : outv);
                    const float* bp = sel == 0 ? bias : (sel == 1 ? biask : biasv);
                    store_val(op + m * 1024 + nn, val + bp[nn]);
                } else {
                    val += bias[n];
                    if constexpr (RELU) val = fmaxf(val, 0.f);
                    if constexpr (RESID) val += bf2f(resid[m * (long)N + n]);
                    store_val(out + m * (long)N + n, val);
                }
            }
        }
    }
}

// ---------------------------------------------------------------------------
// MFMA local causal attention (unchanged from round 6 -- verified).
// ---------------------------------------------------------------------------
__global__ __launch_bounds__(512) void attn_mfma(
    bf16* __restrict__ q, const bf16* __restrict__ k,
    const bf16* __restrict__ v) {
    constexpr int LDK = 72;
    __shared__ bf16 Ks[64][LDK];
    __shared__ bf16 Vt[64][LDK];
    __shared__ bf16 Ps[8][16][LDK];

    const int tid = threadIdx.x;
    const int wid = tid >> 6, lane = tid & 63;
    const int quad = lane >> 4, l16 = lane & 15;
    const int orig = blockIdx.x;
    const int swzb = (orig & 7) * ((int)gridDim.x >> 3) + (orig >> 3);
    const int qt = swzb & 31;          // S/128 = 32 query tiles
    const int bh = swzb >> 5;
    const int b_ = bh >> 4, h_ = bh & 15;
    const int qbase = qt * 128;
    const int wstart = qbase & ~(WIN - 1);
    const int kstart = (wstart == 0) ? 0 : wstart - WIN;
    const int ntiles = (qbase + 128 - kstart) >> 6;

    const long headoff = (long)h_ * DH;

    const bf16* qrow = q + ((long)b_ * S + qbase + wid * 16 + l16) * D + headoff + quad * 8;
    const bfv8 qa0 = *(const bfv8*)qrow;
    const bfv8 qa1 = *(const bfv8*)(qrow + 32);

    const int skey = tid >> 3;
    const int sdp  = (tid & 7) * 8;
    const int vkey = tid & 63;
    const int vdg  = tid >> 6;

    const bf16* kbase = k + (long)b_ * S * D + headoff;
    const bf16* vbase = v + (long)b_ * S * D + headoff;

    f32x4 o[4] = {};
    float lacc[4] = {};
    const int qp = qbase + wid * 16 + quad * 4;

    uint4 kreg = *(const uint4*)(kbase + (long)(kstart + skey) * D + sdp);
    uint4 vreg = *(const uint4*)(vbase + (long)(kstart + vkey) * D + vdg * 8);

    for (int t = 0; t < ntiles; ++t) {
        *(uint4*)&Ks[skey][sdp] = kreg;
        {
            bf16 vv[8];
            *(uint4*)&vv[0] = vreg;
#pragma unroll
            for (int i = 0; i < 8; ++i) Vt[vdg * 8 + i][vkey] = vv[i];
        }
        __syncthreads();

        if (t + 1 < ntiles) {
            const int kn = kstart + (t + 1) * 64;
            kreg = *(const uint4*)(kbase + (long)(kn + skey) * D + sdp);
            vreg = *(const uint4*)(vbase + (long)(kn + vkey) * D + vdg * 8);
        }

        const int kpos0 = kstart + t * 64;

#pragma unroll
        for (int c = 0; c < 4; ++c) {
            const bfv8 kb0 = *(const bfv8*)&Ks[c * 16 + l16][quad * 8];
            const bfv8 kb1 = *(const bfv8*)&Ks[c * 16 + l16][quad * 8 + 32];
            f32x4 s = {};
            __builtin_amdgcn_s_setprio(1);
            s = __builtin_amdgcn_mfma_f32_16x16x32_bf16(qa0, kb0, s, 0, 0, 0);
            s = __builtin_amdgcn_mfma_f32_16x16x32_bf16(qa1, kb1, s, 0, 0, 0);
            __builtin_amdgcn_s_setprio(0);
            const int kp = kpos0 + c * 16 + l16;
#pragma unroll
            for (int r = 0; r < 4; ++r) {
                const float p = (kp <= qp + r)
                    ? exp2f(fmaf(s[r], 0.18033688f, -23.083120f)) : 0.f;
                lacc[r] += p;
                Ps[wid][quad * 4 + r][c * 16 + l16] = __float2bfloat16(p);
            }
        }

#pragma unroll
        for (int c2 = 0; c2 < 2; ++c2) {
            const bfv8 pa = *(const bfv8*)&Ps[wid][l16][c2 * 32 + quad * 8];
            bfv8 vb[4];
#pragma unroll
            for (int dc = 0; dc < 4; ++dc)
                vb[dc] = *(const bfv8*)&Vt[dc * 16 + l16][c2 * 32 + quad * 8];
            __builtin_amdgcn_s_setprio(1);
#pragma unroll
            for (int dc = 0; dc < 4; ++dc)
                o[dc] = __builtin_amdgcn_mfma_f32_16x16x32_bf16(pa, vb[dc], o[dc], 0, 0, 0);
            __builtin_amdgcn_s_setprio(0);
        }
        __syncthreads();
    }

#pragma unroll
    for (int r = 0; r < 4; ++r) {
#pragma unroll
        for (int m = 1; m < 16; m <<= 1) lacc[r] += __shfl_xor(lacc[r], m, 64);
    }
    float inv[4];
#pragma unroll
    for (int r = 0; r < 4; ++r) inv[r] = 2.f / lacc[r];  // x2 = "attn + attn"

    bf16* orow = q + ((long)b_ * S + qp) * D + headoff;
#pragma unroll
    for (int r = 0; r < 4; ++r)
#pragma unroll
        for (int dc = 0; dc < 4; ++dc)
            orow[(long)r * D + dc * 16 + l16] = __float2bfloat16(o[dc][r] * inv[r]);
}

// ---------------------------------------------------------------------------
// LayerNorm over last dim (1024), biased var, in-place safe.
// ---------------------------------------------------------------------------
template <typename TI, typename TO, bool ADD>
__global__ __launch_bounds__(256) void ln_kernel(
    const TI* in, const float* __restrict__ g, const float* __restrict__ be,
    TO* out, const TI* in2) {
    __shared__ float red[4];
    const long row = blockIdx.x;
    const TI* x = in + row * D;
    const TI* x2 = ADD ? in2 + row * D : nullptr;
    const int tid = threadIdx.x;

    float v[4];
    float s = 0.f;
#pragma unroll
    for (int i = 0; i < 4; ++i) {
        v[i] = (float)x[tid + i * 256];
        if constexpr (ADD) v[i] += (float)x2[tid + i * 256];
        s += v[i];
    }
#pragma unroll
    for (int off = 32; off; off >>= 1) s += __shfl_down(s, off, 64);
    if ((tid & 63) == 0) red[tid >> 6] = s;
    __syncthreads();
    const float mu = (red[0] + red[1] + red[2] + red[3]) * (1.f / D);
    __syncthreads();

    float vs = 0.f;
#pragma unroll
    for (int i = 0; i < 4; ++i) {
        const float d0 = v[i] - mu;
        vs += d0 * d0;
    }
#pragma unroll
    for (int off = 32; off; off >>= 1) vs += __shfl_down(vs, off, 64);
    if ((tid & 63) == 0) red[tid >> 6] = vs;
    __syncthreads();
    const float inv = rsqrtf((red[0] + red[1] + red[2] + red[3]) * (1.f / D) + 1e-5f);

#pragma unroll
    for (int i = 0; i < 4; ++i) {
        const int c = tid + i * 256;
        store_val(out + row * D + c, (v[i] - mu) * inv * g[c] + be[c]);
    }
}

// ---------------------------------------------------------------------------
extern "C" void kernel_launch(void* const* d_in, const int* in_sizes, int n_in,
                              void* d_out, int out_size, void* d_ws, size_t ws_size,
                              hipStream_t stream) {
    const float* src = (const float*)d_in[0];
    const float* wq = (const float*)d_in[1];  const float* bq = (const float*)d_in[2];
    const float* wk = (const float*)d_in[3];  const float* bk = (const float*)d_in[4];
    const float* wv = (const float*)d_in[5];  const float* bv = (const float*)d_in[6];
    const float* w1 = (const float*)d_in[7];  const float* b1 = (const float*)d_in[8];
    const float* w2 = (const float*)d_in[9];  const float* b2 = (const float*)d_in[10];
    const float* g1 = (const float*)d_in[11]; const float* be1 = (const float*)d_in[12];
    const float* g2 = (const float*)d_in[13]; const float* be2 = (const float*)d_in[14];

    // Buffer liveness plan (unchanged from round 6):
    //  ws  (64 MiB): qb/x/z [0,32) | phase1: wqkvb[32,38), srcb[40,56)
    //                              | phase2: w1b[32,40), w2b[40,48)
    //  d_out (64 MiB): phase1: kb[0,32), vb[32,64); phase2: hb[0,64);
    //                  finally LN2 writes f32 y over all of d_out.
    char* ws = (char*)d_ws;
    bf16* qb    = (bf16*)ws;
    bf16* wqkvb = (bf16*)(ws + (32L << 20));
    bf16* srcb  = (bf16*)(ws + (40L << 20));
    bf16* w1b   = (bf16*)(ws + (32L << 20));
    bf16* w2b   = (bf16*)(ws + (40L << 20));
    char* dob   = (char*)d_out;
    bf16* kb    = (bf16*)dob;
    bf16* vb    = (bf16*)(dob + (32L << 20));
    bf16* hb    = (bf16*)dob;

    const dim3 blk(256);
    const dim3 blk512(512);

    // QKV weights -> bf16
    f2b_kernel<<<dim3(512),  blk, 0, stream>>>(wq, wqkvb,            131072);
    f2b_kernel<<<dim3(512),  blk, 0, stream>>>(wk, wqkvb + (1L<<20), 131072);
    f2b_kernel<<<dim3(512),  blk, 0, stream>>>(wv, wqkvb + (2L<<20), 131072);

    // Fused QKV GEMM in 2 row-chunks: [8192,1024] x [3072,1024]^T
    // grid (12,32) = 384 wgs (%8==0)
    for (int ch = 0; ch < NQCH; ++ch) {
        const long off = (long)ch * QCH * D;
        f2b_kernel<<<dim3(QCH * D / 8 / 256), blk, 0, stream>>>(
            src + off, srcb, QCH * D / 8);
        gemm256<bf16, false, false, true, 4>
            <<<dim3(3072 / 256, QCH / 256), blk512, 0, stream>>>(
                srcb, wqkvb, bq, nullptr, qb + off, D, 3072,
                kb + off, vb + off, bk, bv);
    }

    // FFN weights -> bf16 into ws[32,48)
    f2b_kernel<<<dim3(2048), blk, 0, stream>>>(w1, w1b, 524288);
    f2b_kernel<<<dim3(2048), blk, 0, stream>>>(w2, w2b, 524288);

    // MFMA local attention: x = 2*attn (bf16) over Q buffer
    attn_mfma<<<dim3(B * H * (S / 128)), blk512, 0, stream>>>(qb, kb, vb);

    // LN1 in place on qb
    ln_kernel<bf16, bf16, false><<<dim3(M_ROWS), blk, 0, stream>>>(
        qb, g1, be1, qb, nullptr);

    // FFN in 2 chunks of 8192 rows; hb = all of d_out.
    // gemm1 grid (16,32)=512 wgs; gemm2 grid (8,32)=256 wgs (BN=128).
    for (int ch = 0; ch < NFCH; ++ch) {
        bf16* xc = qb + (long)ch * FCH * D;
        gemm256<bf16, true, false, false, 4>
            <<<dim3(4096 / 256, FCH / 256), blk512, 0, stream>>>(
                xc, w1b, b1, nullptr, hb, D, 4 * D, nullptr, nullptr, nullptr, nullptr);
        gemm256<bf16, false, true, false, 2>
            <<<dim3(1024 / 128, FCH / 256), blk512, 0, stream>>>(
                hb, w2b, b2, xc, xc, 4 * D, D, nullptr, nullptr, nullptr, nullptr);
    }

    // LN2 on z (bf16, in qb), write f32 into d_out
    ln_kernel<bf16, float, false><<<dim3(M_ROWS), blk, 0, stream>>>(
        qb, g2, be2, (float*)d_out, nullptr);
}